// Round 12
// baseline (126.217 us; speedup 1.0000x reference)
//
#include <hip/hip_runtime.h>
#include <hip/hip_fp16.h>

#define NBC 14
#define NAC 45
#define KF  52
#define RHO 0.05f
#define TT  4096
#define BB  64
#define CHC 32           // outputs per chain
#define WU  44           // warmup steps
#define NPAIR 64         // chunk pairs per batch
#define NTW (WU + CHC)   // 76 steps per chain
#define SPAN (WU + 2*CHC)// 108: xf range covers both chains
#define XPAD 112         // xf row stride (halfs), mult of 4
#define RING 36          // truncated drive window (dropped taps: ~0.037 kernel weight)
#define LOG2E 1.44269504f

typedef __fp16 v2h __attribute__((ext_vector_type(2)));
typedef float  f2  __attribute__((ext_vector_type(2)));
typedef int    i2v __attribute__((ext_vector_type(2)));

__device__ __forceinline__ v2h bch(unsigned u) { return __builtin_bit_cast(v2h, u); }
__device__ __forceinline__ unsigned bcu(v2h h) { return __builtin_bit_cast(unsigned, h); }
__device__ __forceinline__ v2h pk2(float lo, float hi) {
#if __has_builtin(__builtin_amdgcn_cvt_pkrtz)
  return __builtin_bit_cast(v2h, __builtin_amdgcn_cvt_pkrtz(lo, hi));
#else
  v2h r; r[0] = (__fp16)lo; r[1] = (__fp16)hi; return r;
#endif
}
__device__ __forceinline__ v2h xsum16h(v2h v) {
#if __has_builtin(__builtin_amdgcn_permlane16_swap)
  i2v r = __builtin_amdgcn_permlane16_swap((int)bcu(v), (int)bcu(v), false, false);
  return bch((unsigned)r[0]) + bch((unsigned)r[1]);
#else
  return v + bch((unsigned)__builtin_amdgcn_ds_swizzle((int)bcu(v), (16 << 10) | 0x1f));
#endif
}
__device__ __forceinline__ v2h xsum32h(v2h v) {
#if __has_builtin(__builtin_amdgcn_permlane32_swap)
  i2v r = __builtin_amdgcn_permlane32_swap((int)bcu(v), (int)bcu(v), false, false);
  return bch((unsigned)r[0]) + bch((unsigned)r[1]);
#else
  return v + bch((unsigned)__shfl_xor((int)bcu(v), 32));
#endif
}
__device__ __forceinline__ float exp2_f(float x) {
#if __has_builtin(__builtin_amdgcn_exp2f)
  return __builtin_amdgcn_exp2f(x);
#else
  return exp2f(x);
#endif
}

// LDS pool (bytes):
//  [0,    6480)  u ring u32 [NAC][RING], packed (uA,uB) f16  (x-slice overlay in conv)
//  [6480, 9616)  xf fp16 [NBC][XPAD]
//  [9616, 9872)  acr u32 [64]  (gather buffer; entries 45..63 stay zero)
//  [9872, 9936)  relr u32 [16] (entries 14,15 stay zero)
#define POOL_BYTES 9936

__global__ __launch_bounds__(64, 4)
void bcn_kernel(const float* __restrict__ x,
                const float* __restrict__ bck,
                const float* __restrict__ lss,
                const float* __restrict__ soff,
                const float* __restrict__ lbaw,
                const float* __restrict__ ltr,
                const float* __restrict__ ltd,
                const float* __restrict__ lass,
                const float* __restrict__ asoff,
                const float* __restrict__ labw,
                const float* __restrict__ oscale,
                float* __restrict__ out)
{
  __shared__ __align__(16) char pool[POOL_BYTES];
  unsigned* u_ring = (unsigned*)pool;                  // [NAC][RING]
  float*    x_lds  = (float*)pool;                     // overlay during conv (159 floats)
  __half*   xf_lds = (__half*)(pool + 6480);           // [NBC][XPAD]
  unsigned* acr    = (unsigned*)(pool + 9616);         // [64]
  unsigned* relr   = (unsigned*)(pool + 9872);         // [16]

  const int lid   = threadIdx.x;
  const int c16   = lid & 15;
  const int q     = lid >> 4;
  const int blk   = blockIdx.x;
  const int b     = blk >> 6;            // batch
  const int p     = blk & 63;            // chunk pair
  const int t0A   = p * (2 * CHC);       // chain A start; B = t0A + CHC
  const int t_begin = t0A - WU;

  // ---- load stimulus slice into overlay (causal zero pad at t<0) ----
  for (int i = lid; i < SPAN + KF - 1; i += 64) {
    int gt = t_begin - (KF - 1) + i;
    x_lds[i] = (gt >= 0) ? x[b * TT + gt] : 0.f;
  }
  __syncthreads();

  // ---- causal conv into xf_lds (fp16), serves both chains ----
  for (int ib = 0; ib < 2; ++ib) {
    int tau = lid + (ib << 6);
    if (tau < SPAN) {
      float acc[NBC];
#pragma unroll
      for (int c = 0; c < NBC; ++c) acc[c] = 0.f;
#pragma unroll 4
      for (int k = 0; k < KF; ++k) {
        float xv = x_lds[tau + k];
#pragma unroll
        for (int c = 0; c < NBC; ++c) acc[c] = fmaf(bck[c * KF + k], xv, acc[c]);
      }
#pragma unroll
      for (int c = 0; c < NBC; ++c) xf_lds[c * XPAD + tau] = __float2half(acc[c]);
    }
  }
  __syncthreads();

  // ---- zero u ring + acr + relr (x overlay dead now) ----
  for (int i = lid; i < NAC * RING; i += 64) u_ring[i] = 0u;
  if (lid < 64) acr[lid] = 0u;
  if (lid < 16) relr[lid] = 0u;

  // ---- per-lane parameters ----
  float slope2 = 0.f, soff2 = 0.f, osc_c = 0.f;
  f2 poolA; poolA.x = 1.f; poolA.y = 1.f;      // (BCN pool, LNR pool), chain A
  f2 poolB; poolB.x = 1.f; poolB.y = 1.f;
  f2 SA; SA.x = 0.f; SA.y = 0.f;               // (S1,S2) chain A
  f2 SB; SB.x = 0.f; SB.y = 0.f;
  f2 rv2, cn2, co2; rv2.x = rv2.y = cn2.x = cn2.y = co2.x = co2.y = 0.f;
  float Adrv2 = 0.f, Boff2 = 0.f;
  v2h wfbh[16];  // fb weights (w,w): j -> -exp(labw[c16][16q+j])
  v2h wuh[NBC];  // u  weights (w,w): c -> exp(lbaw[lid][c])
  f2 yst[4], fst[4], lst[4];                   // register output staging
  unsigned acst[4];

#pragma unroll
  for (int j = 0; j < 16; ++j) wfbh[j] = pk2(0.f, 0.f);
#pragma unroll
  for (int c = 0; c < NBC; ++c) wuh[c] = pk2(0.f, 0.f);

  if (c16 < NBC) {
    float sl = expf(lss[c16]);
    slope2 = sl * LOG2E;
    soff2  = soff[c16] * sl * LOG2E;
    osc_c  = oscale[c16];
#pragma unroll
    for (int j = 0; j < 16; ++j) {
      int a = 16 * q + j;
      if (a < NAC) { float w = -expf(labw[c16 * NAC + a]); wfbh[j] = pk2(w, w); }
    }
  }
  if (lid < NAC) {
    float tr = expf(ltr[lid]);
    float td = expf(ltd[lid]);
    float a1 = 1.f / td;
    float gg = (td + tr) / (td * tr);
    rv2.x = expf(-a1 * 0.015625f);  rv2.y = expf(-gg * 0.015625f);
    cn2.x = expf(-a1 * 0.003125f);  cn2.y = expf(-gg * 0.003125f);
    // truncated window: remove tap at age RING: cn * r^RING
    co2.x = expf(-a1 * (0.003125f + RING / 64.0f));
    co2.y = expf(-gg * (0.003125f + RING / 64.0f));
    float nrm = 0.f;
    for (int k = 0; k < KF; ++k) {
      float kt = 0.8f - (float)k * 0.015625f;
      float d = expf(-a1 * kt) - expf(-gg * kt);
      nrm = fmaf(d, d, nrm);
    }
    float inorm  = 1.f / sqrtf(nrm);             // norm over full 52-tap kernel
    float aslope = expf(lass[lid]);
    Adrv2 = aslope * inorm * LOG2E;
    Boff2 = aslope * asoff[lid] * LOG2E;
#pragma unroll
    for (int c = 0; c < NBC; ++c) {
      float w = expf(lbaw[lid * NBC + c]);
      wuh[c] = pk2(w, w);
    }
  }

  float* yb  = out;
  float* fbp = out + (size_t)BB * TT * NBC;
  float* acp = out + 2 * (size_t)BB * TT * NBC;
  float* ylp = out + 2 * (size_t)BB * TT * NBC + (size_t)BB * TT * NAC;

  __syncthreads();

  // ---- one dual-chain recurrence step (slot4 literal after unroll) ----
  auto step = [&](int slot4, int rslot, float xfA, float xfB, float uoA, float uoB,
                  bool emit) __attribute__((always_inline)) {
    float mzA = fmaf(-Adrv2, SA.x - SA.y, Boff2);
    float mzB = fmaf(-Adrv2, SB.x - SB.y, Boff2);
    float acA = __fdividef(1.f, 1.f + exp2_f(mzA));
    float acB = __fdividef(1.f, 1.f + exp2_f(mzB));
    if (lid < NAC) acr[lid] = bcu(pk2(acA, acB));

    // fb[c16]: row partial over 16 packed ACs -> 4 b128 + 16 pk_fma_f16
    const uint4* ab = (const uint4*)(acr + (q << 4));
    uint4 A0 = ab[0], A1 = ab[1], A2 = ab[2], A3 = ab[3];
    v2h g0 = wfbh[0] * bch(A0.x);
    v2h g1 = wfbh[1] * bch(A0.y);
    g0 += wfbh[2]  * bch(A0.z);  g1 += wfbh[3]  * bch(A0.w);
    g0 += wfbh[4]  * bch(A1.x);  g1 += wfbh[5]  * bch(A1.y);
    g0 += wfbh[6]  * bch(A1.z);  g1 += wfbh[7]  * bch(A1.w);
    g0 += wfbh[8]  * bch(A2.x);  g1 += wfbh[9]  * bch(A2.y);
    g0 += wfbh[10] * bch(A2.z);  g1 += wfbh[11] * bch(A2.w);
    g0 += wfbh[12] * bch(A3.x);  g1 += wfbh[13] * bch(A3.y);
    g0 += wfbh[14] * bch(A3.z);  g1 += wfbh[15] * bch(A3.w);
    v2h gs = xsum32h(xsum16h(g0 + g1));
    float fbA = (float)gs[0], fbB = (float)gs[1];

    // BC + LNR sigmoids and pool recurrences
    float mlzA = fmaf(-slope2, xfA, soff2);
    float mpzA = fmaf(-slope2, fbA, mlzA);
    float mlzB = fmaf(-slope2, xfB, soff2);
    float mpzB = fmaf(-slope2, fbB, mlzB);
    f2 pvA, pvB;
    pvA.x = __fdividef(1.f, 1.f + exp2_f(mpzA));
    pvA.y = __fdividef(1.f, 1.f + exp2_f(mlzA));
    pvB.x = __fdividef(1.f, 1.f + exp2_f(mpzB));
    pvB.y = __fdividef(1.f, 1.f + exp2_f(mlzB));
    f2 p2A = poolA * (1.f - RHO) + RHO;
    f2 p2B = poolB * (1.f - RHO) + RHO;
    f2 rvA = pvA * p2A, rvB = pvB * p2B;
    poolA = p2A - rvA;  poolB = p2B - rvB;
    if (lid < NBC) relr[lid] = bcu(pk2(rvA.x, rvB.x));
    if (emit) {                      // register staging, static indices
      f2 t1; t1.x = osc_c * rvA.x; t1.y = osc_c * rvB.x; yst[slot4] = t1;
      f2 t2; t2.x = fbA;           t2.y = fbB;           fst[slot4] = t2;
      f2 t3; t3.x = osc_c * rvA.y; t3.y = osc_c * rvB.y; lst[slot4] = t3;
      acst[slot4] = bcu(pk2(acA, acB));
    }

    // u[lid]: 4 b128 + 14 pk_fma_f16
    const uint4* rb = (const uint4*)relr;
    uint4 R0 = rb[0], R1 = rb[1], R2 = rb[2], R3 = rb[3];
    v2h h0 = wuh[0] * bch(R0.x);
    v2h h1 = wuh[1] * bch(R0.y);
    h0 += wuh[2]  * bch(R0.z);  h1 += wuh[3]  * bch(R0.w);
    h0 += wuh[4]  * bch(R1.x);  h1 += wuh[5]  * bch(R1.y);
    h0 += wuh[6]  * bch(R1.z);  h1 += wuh[7]  * bch(R1.w);
    h0 += wuh[8]  * bch(R2.x);  h1 += wuh[9]  * bch(R2.y);
    h0 += wuh[10] * bch(R2.z);  h1 += wuh[11] * bch(R2.w);
    h0 += wuh[12] * bch(R3.x);  h1 += wuh[13] * bch(R3.y);
    v2h uh = h0 + h1;
    float uA = (float)uh[0], uB = (float)uh[1];
    if (lid < NAC) {
      u_ring[lid * RING + rslot] = bcu(uh);
      SA = SA * rv2 + (cn2 * uA - co2 * uoA);
      SB = SB * rv2 + (cn2 * uB - co2 * uoB);
    }
  };

  // ---- 4-step group: batched xf + ring reads ----
  auto group = [&](int s4, int r4, bool emit) __attribute__((always_inline)) {
    uint2 xa = *(const uint2*)&xf_lds[c16 * XPAD + s4];
    uint2 xb = *(const uint2*)&xf_lds[c16 * XPAD + s4 + CHC];
    int roff = ((lid < NAC) ? lid : 0) * RING + r4;
    uint4 ur = *(const uint4*)&u_ring[roff];
    v2h xA01 = bch(xa.x), xA23 = bch(xa.y);
    v2h xB01 = bch(xb.x), xB23 = bch(xb.y);
    v2h u0 = bch(ur.x), u1 = bch(ur.y), u2 = bch(ur.z), u3 = bch(ur.w);
    step(0, r4 + 0, (float)xA01[0], (float)xB01[0], (float)u0[0], (float)u0[1], emit);
    step(1, r4 + 1, (float)xA01[1], (float)xB01[1], (float)u1[0], (float)u1[1], emit);
    step(2, r4 + 2, (float)xA23[0], (float)xB23[0], (float)u2[0], (float)u2[1], emit);
    step(3, r4 + 3, (float)xA23[1], (float)xB23[1], (float)u3[0], (float)u3[1], emit);
  };

  // ---- warm phase ----
  int r4 = 0;
  for (int s4 = 0; s4 < WU; s4 += 4) {
    group(s4, r4, false);
    r4 += 4; if (r4 == RING) r4 = 0;
  }

  // chunk-0 exact start: reset chain A state and zero its ring halves
  if (p == 0) {
    SA.x = 0.f; SA.y = 0.f;
    poolA.x = 1.f; poolA.y = 1.f;
    for (int i = lid; i < NAC * RING; i += 64) u_ring[i] &= 0xFFFF0000u;
    __syncthreads();
  }

  // ---- emit phase ----
  for (int s4 = WU; s4 < NTW; s4 += 4) {
    group(s4, r4, true);
    r4 += 4; if (r4 == RING) r4 = 0;

    // flush 4 staged steps for both chains, straight from registers
    int tgA = t0A + (s4 - WU);
    size_t baseA = (size_t)b * TT + tgA;
    size_t obA = baseA * NBC + c16;
    size_t oaA = baseA * NAC + lid;
    if (lid < NBC) {
#pragma unroll
      for (int sl = 0; sl < 4; ++sl) {
        yb [obA + sl * NBC]                   = yst[sl].x;
        yb [obA + (size_t)CHC * NBC + sl * NBC] = yst[sl].y;
        fbp[obA + sl * NBC]                   = fst[sl].x;
        fbp[obA + (size_t)CHC * NBC + sl * NBC] = fst[sl].y;
        ylp[obA + sl * NBC]                   = lst[sl].x;
        ylp[obA + (size_t)CHC * NBC + sl * NBC] = lst[sl].y;
      }
    }
    if (lid < NAC) {
#pragma unroll
      for (int sl = 0; sl < 4; ++sl) {
        v2h h = bch(acst[sl]);
        acp[oaA + sl * NAC]                   = (float)h[0];
        acp[oaA + (size_t)CHC * NAC + sl * NAC] = (float)h[1];
      }
    }
  }
}

extern "C" void kernel_launch(void* const* d_in, const int* in_sizes, int n_in,
                              void* d_out, int out_size, void* d_ws, size_t ws_size,
                              hipStream_t stream) {
  (void)in_sizes; (void)n_in; (void)d_ws; (void)ws_size; (void)out_size;
  bcn_kernel<<<dim3(BB * NPAIR), dim3(64), 0, stream>>>(
      (const float*)d_in[0],  // x
      (const float*)d_in[1],  // bc_kernels
      (const float*)d_in[2],  // log_sigmoid_slope
      (const float*)d_in[3],  // sigmoid_offset
      (const float*)d_in[4],  // log_bc_ac_weight
      (const float*)d_in[5],  // log_ac_tau_rise
      (const float*)d_in[6],  // log_ac_tau_decay
      (const float*)d_in[7],  // log_ac_sigmoid_slope
      (const float*)d_in[8],  // ac_sigmoid_offset
      (const float*)d_in[9],  // log_ac_bc_weight
      (const float*)d_in[10], // out_scale
      (float*)d_out);
}

// Round 13
// 107.793 us; speedup vs baseline: 1.1709x; 1.1709x over previous
//
#include <hip/hip_runtime.h>
#include <hip/hip_fp16.h>

#define NBC 14
#define NAC 45
#define KF  52
#define RHO 0.05f
#define TT  4096
#define BB  64
#define CHC 64           // outputs per chain
#define WU  44           // warmup steps (pool err ~(0.92)^44*0.66 -> y ~1e-3)
#define NPAIR 32         // chunk pairs per batch
#define NTW (WU + CHC)   // 108 steps per chain
#define SPAN (WU + 2*CHC)// 172: xf range covers both chains
#define XPAD 176         // xf row stride (halfs), mult of 4
#define RING 52          // exact drive window
#define LOG2E 1.44269504f

typedef __fp16 v2h __attribute__((ext_vector_type(2)));
typedef float  f2  __attribute__((ext_vector_type(2)));
typedef int    i2v __attribute__((ext_vector_type(2)));

__device__ __forceinline__ v2h bch(unsigned u) { return __builtin_bit_cast(v2h, u); }
__device__ __forceinline__ unsigned bcu(v2h h) { return __builtin_bit_cast(unsigned, h); }
__device__ __forceinline__ v2h pk2(float lo, float hi) {
#if __has_builtin(__builtin_amdgcn_cvt_pkrtz)
  return __builtin_bit_cast(v2h, __builtin_amdgcn_cvt_pkrtz(lo, hi));
#else
  v2h r; r[0] = (__fp16)lo; r[1] = (__fp16)hi; return r;
#endif
}
__device__ __forceinline__ v2h xsum16h(v2h v) {
#if __has_builtin(__builtin_amdgcn_permlane16_swap)
  i2v r = __builtin_amdgcn_permlane16_swap((int)bcu(v), (int)bcu(v), false, false);
  return bch((unsigned)r[0]) + bch((unsigned)r[1]);
#else
  return v + bch((unsigned)__builtin_amdgcn_ds_swizzle((int)bcu(v), (16 << 10) | 0x1f));
#endif
}
__device__ __forceinline__ v2h xsum32h(v2h v) {
#if __has_builtin(__builtin_amdgcn_permlane32_swap)
  i2v r = __builtin_amdgcn_permlane32_swap((int)bcu(v), (int)bcu(v), false, false);
  return bch((unsigned)r[0]) + bch((unsigned)r[1]);
#else
  return v + bch((unsigned)__shfl_xor((int)bcu(v), 32));
#endif
}
__device__ __forceinline__ float exp2_f(float x) {
#if __has_builtin(__builtin_amdgcn_exp2f)
  return __builtin_amdgcn_exp2f(x);
#else
  return exp2f(x);
#endif
}

// LDS pool (bytes):
//  [0,     9360)  u ring u32 [NAC][RING], packed (uA,uB) f16  (x-slice overlay in conv)
//  [9360, 14288)  xf fp16 [NBC][XPAD]
//  [14288,14544)  acr u32 [64]  (gather buffer; entries 45..63 stay zero)
//  [14544,14608)  relr u32 [16] (entries 14,15 stay zero)
#define POOL_BYTES 14608

__global__ __launch_bounds__(64)
void bcn_kernel(const float* __restrict__ x,
                const float* __restrict__ bck,
                const float* __restrict__ lss,
                const float* __restrict__ soff,
                const float* __restrict__ lbaw,
                const float* __restrict__ ltr,
                const float* __restrict__ ltd,
                const float* __restrict__ lass,
                const float* __restrict__ asoff,
                const float* __restrict__ labw,
                const float* __restrict__ oscale,
                float* __restrict__ out)
{
  __shared__ __align__(16) char pool[POOL_BYTES];
  unsigned* u_ring = (unsigned*)pool;                  // [NAC][RING]
  float*    x_lds  = (float*)pool;                     // overlay during conv (223 floats)
  __half*   xf_lds = (__half*)(pool + 9360);           // [NBC][XPAD]
  unsigned* acr    = (unsigned*)(pool + 14288);        // [64]
  unsigned* relr   = (unsigned*)(pool + 14544);        // [16]

  const int lid   = threadIdx.x;
  const int c16   = lid & 15;
  const int q     = lid >> 4;
  const int blk   = blockIdx.x;
  const int b     = blk >> 5;            // batch
  const int p     = blk & 31;            // chunk pair
  const int t0A   = p * (2 * CHC);       // chain A start; B = t0A + CHC
  const int t_begin = t0A - WU;

  // ---- load stimulus slice into overlay (causal zero pad at t<0) ----
  for (int i = lid; i < SPAN + KF - 1; i += 64) {
    int gt = t_begin - (KF - 1) + i;
    x_lds[i] = (gt >= 0) ? x[b * TT + gt] : 0.f;
  }
  __syncthreads();

  // ---- causal conv into xf_lds (fp16), serves both chains ----
  for (int ib = 0; ib < 3; ++ib) {
    int tau = lid + (ib << 6);
    if (tau < SPAN) {
      float acc[NBC];
#pragma unroll
      for (int c = 0; c < NBC; ++c) acc[c] = 0.f;
#pragma unroll 4
      for (int k = 0; k < KF; ++k) {
        float xv = x_lds[tau + k];
#pragma unroll
        for (int c = 0; c < NBC; ++c) acc[c] = fmaf(bck[c * KF + k], xv, acc[c]);
      }
#pragma unroll
      for (int c = 0; c < NBC; ++c) xf_lds[c * XPAD + tau] = __float2half(acc[c]);
    }
  }
  __syncthreads();

  // ---- zero u ring + acr + relr (x overlay dead now) ----
  for (int i = lid; i < NAC * RING; i += 64) u_ring[i] = 0u;
  if (lid < 64) acr[lid] = 0u;
  if (lid < 16) relr[lid] = 0u;

  // ---- per-lane parameters ----
  float slope2 = 0.f, soff2 = 0.f, osc_c = 0.f;
  f2 poolA; poolA.x = 1.f; poolA.y = 1.f;      // (BCN pool, LNR pool), chain A
  f2 poolB; poolB.x = 1.f; poolB.y = 1.f;
  f2 SA; SA.x = 0.f; SA.y = 0.f;               // (S1,S2) chain A
  f2 SB; SB.x = 0.f; SB.y = 0.f;
  f2 rv2, cn2, co2; rv2.x = rv2.y = cn2.x = cn2.y = co2.x = co2.y = 0.f;
  float Adrv2 = 0.f, Boff2 = 0.f;
  v2h wfbh[16];  // fb weights (w,w): j -> -exp(labw[c16][16q+j])
  v2h wuh[NBC];  // u  weights (w,w): c -> exp(lbaw[lid][c])
  f2 yst[4], fst[4], lst[4];                   // register output staging
  unsigned acst[4];

#pragma unroll
  for (int j = 0; j < 16; ++j) wfbh[j] = pk2(0.f, 0.f);
#pragma unroll
  for (int c = 0; c < NBC; ++c) wuh[c] = pk2(0.f, 0.f);

  if (c16 < NBC) {
    float sl = expf(lss[c16]);
    slope2 = sl * LOG2E;
    soff2  = soff[c16] * sl * LOG2E;
    osc_c  = oscale[c16];
#pragma unroll
    for (int j = 0; j < 16; ++j) {
      int a = 16 * q + j;
      if (a < NAC) { float w = -expf(labw[c16 * NAC + a]); wfbh[j] = pk2(w, w); }
    }
  }
  if (lid < NAC) {
    float tr = expf(ltr[lid]);
    float td = expf(ltd[lid]);
    float a1 = 1.f / td;
    float gg = (td + tr) / (td * tr);
    rv2.x = expf(-a1 * 0.015625f);  rv2.y = expf(-gg * 0.015625f);
    cn2.x = expf(-a1 * 0.003125f);  cn2.y = expf(-gg * 0.003125f);
    co2.x = expf(-a1 * 0.815625f);  co2.y = expf(-gg * 0.815625f);
    float nrm = 0.f;
    for (int k = 0; k < KF; ++k) {
      float kt = 0.8f - (float)k * 0.015625f;
      float d = expf(-a1 * kt) - expf(-gg * kt);
      nrm = fmaf(d, d, nrm);
    }
    float inorm  = 1.f / sqrtf(nrm);
    float aslope = expf(lass[lid]);
    Adrv2 = aslope * inorm * LOG2E;
    Boff2 = aslope * asoff[lid] * LOG2E;
#pragma unroll
    for (int c = 0; c < NBC; ++c) {
      float w = expf(lbaw[lid * NBC + c]);
      wuh[c] = pk2(w, w);
    }
  }

  float* yb  = out;
  float* fbp = out + (size_t)BB * TT * NBC;
  float* acp = out + 2 * (size_t)BB * TT * NBC;
  float* ylp = out + 2 * (size_t)BB * TT * NBC + (size_t)BB * TT * NAC;

  __syncthreads();

  // ---- one dual-chain recurrence step (slot4 literal after unroll) ----
  auto step = [&](int slot4, int rslot, float xfA, float xfB, float uoA, float uoB,
                  bool emit) __attribute__((always_inline)) {
    float mzA = fmaf(-Adrv2, SA.x - SA.y, Boff2);
    float mzB = fmaf(-Adrv2, SB.x - SB.y, Boff2);
    float acA = __fdividef(1.f, 1.f + exp2_f(mzA));
    float acB = __fdividef(1.f, 1.f + exp2_f(mzB));
    if (lid < NAC) acr[lid] = bcu(pk2(acA, acB));

    // fb[c16]: row partial over 16 packed ACs -> 4 b128 + 16 pk_fma_f16
    const uint4* ab = (const uint4*)(acr + (q << 4));
    uint4 A0 = ab[0], A1 = ab[1], A2 = ab[2], A3 = ab[3];
    v2h g0 = wfbh[0] * bch(A0.x);
    v2h g1 = wfbh[1] * bch(A0.y);
    g0 += wfbh[2]  * bch(A0.z);  g1 += wfbh[3]  * bch(A0.w);
    g0 += wfbh[4]  * bch(A1.x);  g1 += wfbh[5]  * bch(A1.y);
    g0 += wfbh[6]  * bch(A1.z);  g1 += wfbh[7]  * bch(A1.w);
    g0 += wfbh[8]  * bch(A2.x);  g1 += wfbh[9]  * bch(A2.y);
    g0 += wfbh[10] * bch(A2.z);  g1 += wfbh[11] * bch(A2.w);
    g0 += wfbh[12] * bch(A3.x);  g1 += wfbh[13] * bch(A3.y);
    g0 += wfbh[14] * bch(A3.z);  g1 += wfbh[15] * bch(A3.w);
    v2h gs = xsum32h(xsum16h(g0 + g1));
    float fbA = (float)gs[0], fbB = (float)gs[1];

    // BC + LNR sigmoids and pool recurrences
    float mlzA = fmaf(-slope2, xfA, soff2);
    float mpzA = fmaf(-slope2, fbA, mlzA);
    float mlzB = fmaf(-slope2, xfB, soff2);
    float mpzB = fmaf(-slope2, fbB, mlzB);
    f2 pvA, pvB;
    pvA.x = __fdividef(1.f, 1.f + exp2_f(mpzA));
    pvA.y = __fdividef(1.f, 1.f + exp2_f(mlzA));
    pvB.x = __fdividef(1.f, 1.f + exp2_f(mpzB));
    pvB.y = __fdividef(1.f, 1.f + exp2_f(mlzB));
    f2 p2A = poolA * (1.f - RHO) + RHO;
    f2 p2B = poolB * (1.f - RHO) + RHO;
    f2 rvA = pvA * p2A, rvB = pvB * p2B;
    poolA = p2A - rvA;  poolB = p2B - rvB;
    if (lid < NBC) relr[lid] = bcu(pk2(rvA.x, rvB.x));
    if (emit) {                      // register staging, static indices
      f2 t1; t1.x = osc_c * rvA.x; t1.y = osc_c * rvB.x; yst[slot4] = t1;
      f2 t2; t2.x = fbA;           t2.y = fbB;           fst[slot4] = t2;
      f2 t3; t3.x = osc_c * rvA.y; t3.y = osc_c * rvB.y; lst[slot4] = t3;
      acst[slot4] = bcu(pk2(acA, acB));
    }

    // u[lid]: 4 b128 + 14 pk_fma_f16
    const uint4* rb = (const uint4*)relr;
    uint4 R0 = rb[0], R1 = rb[1], R2 = rb[2], R3 = rb[3];
    v2h h0 = wuh[0] * bch(R0.x);
    v2h h1 = wuh[1] * bch(R0.y);
    h0 += wuh[2]  * bch(R0.z);  h1 += wuh[3]  * bch(R0.w);
    h0 += wuh[4]  * bch(R1.x);  h1 += wuh[5]  * bch(R1.y);
    h0 += wuh[6]  * bch(R1.z);  h1 += wuh[7]  * bch(R1.w);
    h0 += wuh[8]  * bch(R2.x);  h1 += wuh[9]  * bch(R2.y);
    h0 += wuh[10] * bch(R2.z);  h1 += wuh[11] * bch(R2.w);
    h0 += wuh[12] * bch(R3.x);  h1 += wuh[13] * bch(R3.y);
    v2h uh = h0 + h1;
    float uA = (float)uh[0], uB = (float)uh[1];
    if (lid < NAC) {
      u_ring[lid * RING + rslot] = bcu(uh);
      SA = SA * rv2 + (cn2 * uA - co2 * uoA);
      SB = SB * rv2 + (cn2 * uB - co2 * uoB);
    }
  };

  // ---- 4-step group: batched xf + ring reads ----
  auto group = [&](int s4, int r4, bool emit) __attribute__((always_inline)) {
    uint2 xa = *(const uint2*)&xf_lds[c16 * XPAD + s4];
    uint2 xb = *(const uint2*)&xf_lds[c16 * XPAD + s4 + CHC];
    int roff = ((lid < NAC) ? lid : 0) * RING + r4;
    uint4 ur = *(const uint4*)&u_ring[roff];
    v2h xA01 = bch(xa.x), xA23 = bch(xa.y);
    v2h xB01 = bch(xb.x), xB23 = bch(xb.y);
    v2h u0 = bch(ur.x), u1 = bch(ur.y), u2 = bch(ur.z), u3 = bch(ur.w);
    step(0, r4 + 0, (float)xA01[0], (float)xB01[0], (float)u0[0], (float)u0[1], emit);
    step(1, r4 + 1, (float)xA01[1], (float)xB01[1], (float)u1[0], (float)u1[1], emit);
    step(2, r4 + 2, (float)xA23[0], (float)xB23[0], (float)u2[0], (float)u2[1], emit);
    step(3, r4 + 3, (float)xA23[1], (float)xB23[1], (float)u3[0], (float)u3[1], emit);
  };

  // ---- warm phase ----
  int r4 = 0;
  for (int s4 = 0; s4 < WU; s4 += 4) {
    group(s4, r4, false);
    r4 += 4; if (r4 == RING) r4 = 0;
  }

  // chunk-0 exact start: reset chain A state and zero its ring halves
  if (p == 0) {
    SA.x = 0.f; SA.y = 0.f;
    poolA.x = 1.f; poolA.y = 1.f;
    for (int i = lid; i < NAC * RING; i += 64) u_ring[i] &= 0xFFFF0000u;
  }

  // ---- emit phase ----
  for (int s4 = WU; s4 < NTW; s4 += 4) {
    group(s4, r4, true);
    r4 += 4; if (r4 == RING) r4 = 0;

    // flush 4 staged steps for both chains, straight from registers
    int tgA = t0A + (s4 - WU);
    size_t baseA = (size_t)b * TT + tgA;
    size_t obA = baseA * NBC + c16;
    size_t oaA = baseA * NAC + lid;
    if (lid < NBC) {
#pragma unroll
      for (int sl = 0; sl < 4; ++sl) {
        yb [obA + sl * NBC]                     = yst[sl].x;
        yb [obA + (size_t)CHC * NBC + sl * NBC] = yst[sl].y;
        fbp[obA + sl * NBC]                     = fst[sl].x;
        fbp[obA + (size_t)CHC * NBC + sl * NBC] = fst[sl].y;
        ylp[obA + sl * NBC]                     = lst[sl].x;
        ylp[obA + (size_t)CHC * NBC + sl * NBC] = lst[sl].y;
      }
    }
    if (lid < NAC) {
#pragma unroll
      for (int sl = 0; sl < 4; ++sl) {
        v2h h = bch(acst[sl]);
        acp[oaA + sl * NAC]                     = (float)h[0];
        acp[oaA + (size_t)CHC * NAC + sl * NAC] = (float)h[1];
      }
    }
  }
}

extern "C" void kernel_launch(void* const* d_in, const int* in_sizes, int n_in,
                              void* d_out, int out_size, void* d_ws, size_t ws_size,
                              hipStream_t stream) {
  (void)in_sizes; (void)n_in; (void)d_ws; (void)ws_size; (void)out_size;
  bcn_kernel<<<dim3(BB * NPAIR), dim3(64), 0, stream>>>(
      (const float*)d_in[0],  // x
      (const float*)d_in[1],  // bc_kernels
      (const float*)d_in[2],  // log_sigmoid_slope
      (const float*)d_in[3],  // sigmoid_offset
      (const float*)d_in[4],  // log_bc_ac_weight
      (const float*)d_in[5],  // log_ac_tau_rise
      (const float*)d_in[6],  // log_ac_tau_decay
      (const float*)d_in[7],  // log_ac_sigmoid_slope
      (const float*)d_in[8],  // ac_sigmoid_offset
      (const float*)d_in[9],  // log_ac_bc_weight
      (const float*)d_in[10], // out_scale
      (float*)d_out);
}

// Round 14
// 97.405 us; speedup vs baseline: 1.2958x; 1.1066x over previous
//
#include <hip/hip_runtime.h>
#include <hip/hip_fp16.h>

#define NBC 14
#define NAC 45
#define KF  52
#define RHO 0.05f
#define TT  4096
#define BB  64
#define CHC 64           // outputs per chain
#define WU  44           // warmup steps
#define NPAIR 32         // chunk pairs per batch
#define NTW (WU + CHC)   // 108 steps per chain
#define SPAN (WU + 2*CHC)// 172: xf range covers both chains
#define XPAD 176         // xf row stride (halfs), mult of 4
#define RING 52          // logical ring slots (exact window)
#define RINGP 54         // physical row stride in u32 (22 mod 32 -> <=3-way banks)
#define LOG2E 1.44269504f

typedef __fp16 v2h __attribute__((ext_vector_type(2)));
typedef float  f2  __attribute__((ext_vector_type(2)));
typedef int    i2v __attribute__((ext_vector_type(2)));

__device__ __forceinline__ v2h bch(unsigned u) { return __builtin_bit_cast(v2h, u); }
__device__ __forceinline__ unsigned bcu(v2h h) { return __builtin_bit_cast(unsigned, h); }
__device__ __forceinline__ v2h pk2(float lo, float hi) {
#if __has_builtin(__builtin_amdgcn_cvt_pkrtz)
  return __builtin_bit_cast(v2h, __builtin_amdgcn_cvt_pkrtz(lo, hi));
#else
  v2h r; r[0] = (__fp16)lo; r[1] = (__fp16)hi; return r;
#endif
}
__device__ __forceinline__ v2h xsum16h(v2h v) {
#if __has_builtin(__builtin_amdgcn_permlane16_swap)
  i2v r = __builtin_amdgcn_permlane16_swap((int)bcu(v), (int)bcu(v), false, false);
  return bch((unsigned)r[0]) + bch((unsigned)r[1]);
#else
  return v + bch((unsigned)__builtin_amdgcn_ds_swizzle((int)bcu(v), (16 << 10) | 0x1f));
#endif
}
__device__ __forceinline__ v2h xsum32h(v2h v) {
#if __has_builtin(__builtin_amdgcn_permlane32_swap)
  i2v r = __builtin_amdgcn_permlane32_swap((int)bcu(v), (int)bcu(v), false, false);
  return bch((unsigned)r[0]) + bch((unsigned)r[1]);
#else
  return v + bch((unsigned)__shfl_xor((int)bcu(v), 32));
#endif
}
__device__ __forceinline__ float exp2_f(float x) {
#if __has_builtin(__builtin_amdgcn_exp2f)
  return __builtin_amdgcn_exp2f(x);
#else
  return exp2f(x);
#endif
}

// LDS pool (bytes):
//  [0,     9720)  u ring u32 [NAC][RINGP], packed (uA,uB) f16 (x overlay in conv)
//  [9720, 14648)  xf fp16 [NBC][XPAD]
//  [14656,14912)  acr u32 [64] (gather buffer; entries 45..63 stay zero; 16B aligned)
//  [14912,14976)  relr u32 [16] (entries 14,15 stay zero)
#define POOL_BYTES 14976

__global__ __launch_bounds__(64)
void bcn_kernel(const float* __restrict__ x,
                const float* __restrict__ bck,
                const float* __restrict__ lss,
                const float* __restrict__ soff,
                const float* __restrict__ lbaw,
                const float* __restrict__ ltr,
                const float* __restrict__ ltd,
                const float* __restrict__ lass,
                const float* __restrict__ asoff,
                const float* __restrict__ labw,
                const float* __restrict__ oscale,
                float* __restrict__ out)
{
  __shared__ __align__(16) char pool[POOL_BYTES];
  unsigned* u_ring = (unsigned*)pool;                  // [NAC][RINGP]
  float*    x_lds  = (float*)pool;                     // overlay during conv (223 floats)
  __half*   xf_lds = (__half*)(pool + 9720);           // [NBC][XPAD]
  unsigned* acr    = (unsigned*)(pool + 14656);        // [64]
  unsigned* relr   = (unsigned*)(pool + 14912);        // [16]

  const int lid   = threadIdx.x;
  const int c16   = lid & 15;
  const int q     = lid >> 4;
  const float rowm = (q & 1) ? 0.f : 1.f;   // rows 0,2: BCN (with fb); rows 1,3: LNR
  const int blk   = blockIdx.x;
  const int b     = blk >> 5;            // batch
  const int p     = blk & 31;            // chunk pair
  const int t0A   = p * (2 * CHC);       // chain A start; B = t0A + CHC
  const int t_begin = t0A - WU;

  // ---- load stimulus slice into overlay (causal zero pad at t<0) ----
  for (int i = lid; i < SPAN + KF - 1; i += 64) {
    int gt = t_begin - (KF - 1) + i;
    x_lds[i] = (gt >= 0) ? x[b * TT + gt] : 0.f;
  }
  __syncthreads();

  // ---- causal conv into xf_lds (fp16), serves both chains ----
  for (int ib = 0; ib < 3; ++ib) {
    int tau = lid + (ib << 6);
    if (tau < SPAN) {
      float acc[NBC];
#pragma unroll
      for (int c = 0; c < NBC; ++c) acc[c] = 0.f;
#pragma unroll 4
      for (int k = 0; k < KF; ++k) {
        float xv = x_lds[tau + k];
#pragma unroll
        for (int c = 0; c < NBC; ++c) acc[c] = fmaf(bck[c * KF + k], xv, acc[c]);
      }
#pragma unroll
      for (int c = 0; c < NBC; ++c) xf_lds[c * XPAD + tau] = __float2half(acc[c]);
    }
  }
  __syncthreads();

  // ---- zero u ring + acr + relr (x overlay dead now) ----
  for (int i = lid; i < NAC * RINGP; i += 64) u_ring[i] = 0u;
  if (lid < 64) acr[lid] = 0u;
  if (lid < 16) relr[lid] = 0u;

  // ---- per-lane parameters ----
  float slope2 = 0.f, soff2 = 0.f, osc_c = 0.f;
  f2 poolP; poolP.x = 1.f; poolP.y = 1.f;      // role pool (chain A, chain B)
  f2 SA; SA.x = 0.f; SA.y = 0.f;               // (S1,S2) chain A
  f2 SB; SB.x = 0.f; SB.y = 0.f;
  f2 rv2, cn2, co2; rv2.x = rv2.y = cn2.x = cn2.y = co2.x = co2.y = 0.f;
  float Adrv2 = 0.f, Boff2 = 0.f;
  v2h wfbh[16];  // fb weights (w,w): j -> -exp(labw[c16][16q+j])
  v2h wuh[NBC];  // u  weights (w,w): c -> exp(lbaw[lid][c])
  f2 yst[4], fst[4];                           // register output staging
  unsigned acst[4];

#pragma unroll
  for (int j = 0; j < 16; ++j) wfbh[j] = pk2(0.f, 0.f);
#pragma unroll
  for (int c = 0; c < NBC; ++c) wuh[c] = pk2(0.f, 0.f);

  if (c16 < NBC) {
    float sl = expf(lss[c16]);
    slope2 = sl * LOG2E;
    soff2  = soff[c16] * sl * LOG2E;
    osc_c  = oscale[c16];
#pragma unroll
    for (int j = 0; j < 16; ++j) {
      int a = 16 * q + j;
      if (a < NAC) { float w = -expf(labw[c16 * NAC + a]); wfbh[j] = pk2(w, w); }
    }
  }
  if (lid < NAC) {
    float tr = expf(ltr[lid]);
    float td = expf(ltd[lid]);
    float a1 = 1.f / td;
    float gg = (td + tr) / (td * tr);
    rv2.x = expf(-a1 * 0.015625f);  rv2.y = expf(-gg * 0.015625f);
    cn2.x = expf(-a1 * 0.003125f);  cn2.y = expf(-gg * 0.003125f);
    co2.x = expf(-a1 * 0.815625f);  co2.y = expf(-gg * 0.815625f);
    float nrm = 0.f;
    for (int k = 0; k < KF; ++k) {
      float kt = 0.8f - (float)k * 0.015625f;
      float d = expf(-a1 * kt) - expf(-gg * kt);
      nrm = fmaf(d, d, nrm);
    }
    float inorm  = 1.f / sqrtf(nrm);
    float aslope = expf(lass[lid]);
    Adrv2 = aslope * inorm * LOG2E;
    Boff2 = aslope * asoff[lid] * LOG2E;
#pragma unroll
    for (int c = 0; c < NBC; ++c) {
      float w = expf(lbaw[lid * NBC + c]);
      wuh[c] = pk2(w, w);
    }
  }

  float* yb  = out;
  float* fbp = out + (size_t)BB * TT * NBC;
  float* acp = out + 2 * (size_t)BB * TT * NBC;
  float* ylp = out + 2 * (size_t)BB * TT * NBC + (size_t)BB * TT * NAC;

  __syncthreads();

  // ---- one dual-chain recurrence step (role-split BCN/LNR across rows) ----
  auto step = [&](int slot4, int rslot, float xfA, float xfB, float uoA, float uoB,
                  bool emit) __attribute__((always_inline)) {
    float mzA = fmaf(-Adrv2, SA.x - SA.y, Boff2);
    float mzB = fmaf(-Adrv2, SB.x - SB.y, Boff2);
    float acA = __fdividef(1.f, 1.f + exp2_f(mzA));
    float acB = __fdividef(1.f, 1.f + exp2_f(mzB));
    if (lid < NAC) acr[lid] = bcu(pk2(acA, acB));

    // fb[c16]: row partial over 16 packed ACs -> 4 b128 + 16 pk_fma_f16
    const uint4* ab = (const uint4*)(acr + (q << 4));
    uint4 A0 = ab[0], A1 = ab[1], A2 = ab[2], A3 = ab[3];
    v2h g0 = wfbh[0] * bch(A0.x);
    v2h g1 = wfbh[1] * bch(A0.y);
    g0 += wfbh[2]  * bch(A0.z);  g1 += wfbh[3]  * bch(A0.w);
    g0 += wfbh[4]  * bch(A1.x);  g1 += wfbh[5]  * bch(A1.y);
    g0 += wfbh[6]  * bch(A1.z);  g1 += wfbh[7]  * bch(A1.w);
    g0 += wfbh[8]  * bch(A2.x);  g1 += wfbh[9]  * bch(A2.y);
    g0 += wfbh[10] * bch(A2.z);  g1 += wfbh[11] * bch(A2.w);
    g0 += wfbh[12] * bch(A3.x);  g1 += wfbh[13] * bch(A3.y);
    g0 += wfbh[14] * bch(A3.z);  g1 += wfbh[15] * bch(A3.w);
    v2h gs = xsum32h(xsum16h(g0 + g1));
    float fbA = (float)gs[0], fbB = (float)gs[1];

    // role-fused sigmoid: rows 0,2 see fb (BCN), rows 1,3 see 0 (LNR)
    float mA = fmaf(-slope2, fmaf(rowm, fbA, xfA), soff2);
    float mB = fmaf(-slope2, fmaf(rowm, fbB, xfB), soff2);
    f2 pv;
    pv.x = __fdividef(1.f, 1.f + exp2_f(mA));
    pv.y = __fdividef(1.f, 1.f + exp2_f(mB));
    f2 p2 = poolP * (1.f - RHO) + RHO;
    f2 relP = pv * p2;
    poolP = p2 - relP;
    if (lid < NBC) relr[lid] = bcu(pk2(relP.x, relP.y));   // row0 = BCN rel
    if (emit) {
      yst[slot4] = relP * osc_c;          // row0: y_bcn; row1: y_lnr
      f2 t; t.x = fbA; t.y = fbB; fst[slot4] = t;
      acst[slot4] = bcu(pk2(acA, acB));
    }

    // u[lid]: 4 b128 broadcast reads + 14 pk_fma_f16
    const uint4* rb = (const uint4*)relr;
    uint4 R0 = rb[0], R1 = rb[1], R2 = rb[2], R3 = rb[3];
    v2h h0 = wuh[0] * bch(R0.x);
    v2h h1 = wuh[1] * bch(R0.y);
    h0 += wuh[2]  * bch(R0.z);  h1 += wuh[3]  * bch(R0.w);
    h0 += wuh[4]  * bch(R1.x);  h1 += wuh[5]  * bch(R1.y);
    h0 += wuh[6]  * bch(R1.z);  h1 += wuh[7]  * bch(R1.w);
    h0 += wuh[8]  * bch(R2.x);  h1 += wuh[9]  * bch(R2.y);
    h0 += wuh[10] * bch(R2.z);  h1 += wuh[11] * bch(R2.w);
    h0 += wuh[12] * bch(R3.x);  h1 += wuh[13] * bch(R3.y);
    v2h uh = h0 + h1;
    float uA = (float)uh[0], uB = (float)uh[1];
    if (lid < NAC) {
      u_ring[lid * RINGP + rslot] = bcu(uh);
      SA = SA * rv2 + (cn2 * uA - co2 * uoA);
      SB = SB * rv2 + (cn2 * uB - co2 * uoB);
    }
  };

  // ---- 4-step group: batched xf + ring reads (2x b64, 8B aligned) ----
  auto group = [&](int s4, int r4, bool emit) __attribute__((always_inline)) {
    uint2 xa = *(const uint2*)&xf_lds[c16 * XPAD + s4];
    uint2 xb = *(const uint2*)&xf_lds[c16 * XPAD + s4 + CHC];
    int roff = ((lid < NAC) ? lid : 0) * RINGP + r4;
    uint2 ur01 = *(const uint2*)&u_ring[roff];
    uint2 ur23 = *(const uint2*)&u_ring[roff + 2];
    v2h xA01 = bch(xa.x), xA23 = bch(xa.y);
    v2h xB01 = bch(xb.x), xB23 = bch(xb.y);
    v2h u0 = bch(ur01.x), u1 = bch(ur01.y), u2 = bch(ur23.x), u3 = bch(ur23.y);
    step(0, r4 + 0, (float)xA01[0], (float)xB01[0], (float)u0[0], (float)u0[1], emit);
    step(1, r4 + 1, (float)xA01[1], (float)xB01[1], (float)u1[0], (float)u1[1], emit);
    step(2, r4 + 2, (float)xA23[0], (float)xB23[0], (float)u2[0], (float)u2[1], emit);
    step(3, r4 + 3, (float)xA23[1], (float)xB23[1], (float)u3[0], (float)u3[1], emit);
  };

  // ---- warm phase ----
  int r4 = 0;
  for (int s4 = 0; s4 < WU; s4 += 4) {
    group(s4, r4, false);
    r4 += 4; if (r4 == RING) r4 = 0;
  }

  // chunk-0 exact start: reset chain A state and zero its ring halves
  if (p == 0) {
    SA.x = 0.f; SA.y = 0.f;
    poolP.x = 1.f;
    for (int i = lid; i < NAC * RINGP; i += 64) u_ring[i] &= 0xFFFF0000u;
  }

  // ---- emit phase ----
  for (int s4 = WU; s4 < NTW; s4 += 4) {
    group(s4, r4, true);
    r4 += 4; if (r4 == RING) r4 = 0;

    // flush 4 staged steps for both chains, straight from registers
    int tgA = t0A + (s4 - WU);
    size_t baseA = (size_t)b * TT + tgA;
    if (lid < NBC) {                       // row 0: y_bcn + fb
      size_t ob = baseA * NBC + lid;
#pragma unroll
      for (int sl = 0; sl < 4; ++sl) {
        yb [ob + sl * NBC]                     = yst[sl].x;
        yb [ob + (size_t)CHC * NBC + sl * NBC] = yst[sl].y;
        fbp[ob + sl * NBC]                     = fst[sl].x;
        fbp[ob + (size_t)CHC * NBC + sl * NBC] = fst[sl].y;
      }
    } else if (lid >= 16 && lid < 16 + NBC) {  // row 1: y_lnr
      size_t ob = baseA * NBC + (lid - 16);
#pragma unroll
      for (int sl = 0; sl < 4; ++sl) {
        ylp[ob + sl * NBC]                     = yst[sl].x;
        ylp[ob + (size_t)CHC * NBC + sl * NBC] = yst[sl].y;
      }
    }
    if (lid < NAC) {
      size_t oa = baseA * NAC + lid;
#pragma unroll
      for (int sl = 0; sl < 4; ++sl) {
        v2h h = bch(acst[sl]);
        acp[oa + sl * NAC]                     = (float)h[0];
        acp[oa + (size_t)CHC * NAC + sl * NAC] = (float)h[1];
      }
    }
  }
}

extern "C" void kernel_launch(void* const* d_in, const int* in_sizes, int n_in,
                              void* d_out, int out_size, void* d_ws, size_t ws_size,
                              hipStream_t stream) {
  (void)in_sizes; (void)n_in; (void)d_ws; (void)ws_size; (void)out_size;
  bcn_kernel<<<dim3(BB * NPAIR), dim3(64), 0, stream>>>(
      (const float*)d_in[0],  // x
      (const float*)d_in[1],  // bc_kernels
      (const float*)d_in[2],  // log_sigmoid_slope
      (const float*)d_in[3],  // sigmoid_offset
      (const float*)d_in[4],  // log_bc_ac_weight
      (const float*)d_in[5],  // log_ac_tau_rise
      (const float*)d_in[6],  // log_ac_tau_decay
      (const float*)d_in[7],  // log_ac_sigmoid_slope
      (const float*)d_in[8],  // ac_sigmoid_offset
      (const float*)d_in[9],  // log_ac_bc_weight
      (const float*)d_in[10], // out_scale
      (float*)d_out);
}